// Round 11
// baseline (547.959 us; speedup 1.0000x reference)
//
#include <hip/hip_runtime.h>

typedef short short8  __attribute__((ext_vector_type(8)));
typedef float f32x4   __attribute__((ext_vector_type(4)));

#define B_TOTAL 4096
#define T_STEPS 512
#define F_IN    32
#define H_DIM   60
#define KW      92      // F + H
#define BC      16      // batch rows per block
#define HPITCH  72      // h-LDS row pitch in halves (144B rows, 2-way-free)

#define MFMA(A, B, C) __builtin_amdgcn_mfma_f32_16x16x32_bf16((A), (B), (C), 0, 0, 0)

__device__ __forceinline__ unsigned short bf16rne(float f) {
    unsigned int u = __float_as_uint(f);
    u += 0x7FFFu + ((u >> 16) & 1u);
    return (unsigned short)(u >> 16);
}
__device__ __forceinline__ float bf16tof(unsigned short s) {
    return __uint_as_float(((unsigned int)s) << 16);
}
__device__ __forceinline__ float rcpf(float z) {
    return __builtin_amdgcn_rcpf(z);            // v_rcp_f32, 1 ulp
}
__device__ __forceinline__ float exp2f_(float z) {
#if __has_builtin(__builtin_amdgcn_exp2f)
    return __builtin_amdgcn_exp2f(z);           // v_exp_f32
#else
    float r; asm("v_exp_f32 %0, %1" : "=v"(r) : "v"(z)); return r;
#endif
}
// zs pre-scaled by log2e:
__device__ __forceinline__ float sig2(float zs) {      // sigmoid(z), zs=z*log2e
    return rcpf(1.0f + exp2f_(-zs));
}
// zs pre-scaled by 2*log2e:
__device__ __forceinline__ float tanh2(float zs) {     // tanh(z), zs=2z*log2e
    return fmaf(-2.0f, rcpf(1.0f + exp2f_(zs)), 1.0f);
}

// float4 pair -> packed bf16 short8 fragment, RNE, via v_cvt_pk_bf16_f32
#define CVTH(VA, VB, OH)                                                        \
    {                                                                           \
        int4 hp;                                                                \
        asm("v_cvt_pk_bf16_f32 %0, %1, %2" : "=v"(hp.x) : "v"((VA).x), "v"((VA).y)); \
        asm("v_cvt_pk_bf16_f32 %0, %1, %2" : "=v"(hp.y) : "v"((VA).z), "v"((VA).w)); \
        asm("v_cvt_pk_bf16_f32 %0, %1, %2" : "=v"(hp.z) : "v"((VB).x), "v"((VB).y)); \
        asm("v_cvt_pk_bf16_f32 %0, %1, %2" : "=v"(hp.w) : "v"((VB).z), "v"((VB).w)); \
        OH = __builtin_bit_cast(short8, hp);                                    \
    }

__global__ __launch_bounds__(1024, 4)
void lstm_mfma_kernel(const float* __restrict__ x,
                      const float* __restrict__ wk,
                      const float* __restrict__ bias,
                      const float* __restrict__ dense_w,
                      const float* __restrict__ dense_b,
                      float* __restrict__ out)
{
    // Double-buffered h-state, bf16 hi plane only (weights carry the lo plane).
    __shared__ __align__(16) short Hhi[2][BC][HPITCH];
    __shared__ float Hf[BC][64];            // final-step h, f32, for epilogue

    const int tid  = threadIdx.x;
    const int lane = tid & 63;
    const int w    = tid >> 6;              // wave 0..15 = M-tile index
    const int b0   = blockIdx.x * BC;
    const int lm   = lane & 15;             // batch row (B-operand N index)
    const int kg   = lane >> 4;             // K octet group 0..3
    const int lk8  = kg * 8;
    const bool mtok = (w < 15);             // tile 15 is zero pad

    const float LOG2E = 1.44269504088896340736f;

    // ---------------- A fragments = W^T (static), exp2-prescaled, hi+lo -----
    // Wave w owns M-tile w. D-layout: lane (lm,kg) acc regs r=0..3 hold gates
    // i,j,f,o (pre-scaled) of unit u=4*w+kg for batch row b=lm.
    // Gate j scaled by 2*log2e (tanh), others log2e (sigmoid); forget +1 folded.
    short8 wh[3], wl[3];
    f32x4  biasv = {0.f, 0.f, 0.f, 0.f};
    if (mtok) {
        const int uo = 4 * w + kg;
        #pragma unroll
        for (int r = 0; r < 4; ++r) {
            const float sc = (r == 1) ? 2.0f * LOG2E : LOG2E;
            biasv[r] = (bias[r * 60 + uo] + (r == 2 ? 1.0f : 0.0f)) * sc;
        }
        const int c = 16 * w + lm;          // A-operand M-row
        const int u = c >> 2, g = c & 3;
        const float gsc = (g == 1) ? 2.0f * LOG2E : LOG2E;
        #pragma unroll
        for (int s = 0; s < 3; ++s) {
            short8 hv, lv;
            #pragma unroll
            for (int e = 0; e < 8; ++e) {
                const int k = s * 32 + lk8 + e;
                float wv = (k < KW) ? wk[k * 240 + g * 60 + u] * gsc : 0.0f;
                unsigned short hh = bf16rne(wv);
                hv[e] = (short)hh;
                lv[e] = (short)bf16rne(wv - bf16tof(hh));
            }
            wh[s] = hv;
            wl[s] = lv;
        }
    } else {
        #pragma unroll
        for (int s = 0; s < 3; ++s) { wh[s] = (short8)0; wl[s] = (short8)0; }
    }
    const int u4 = 4 * w + kg;              // output unit of this lane

    // ---------------- zero h buffers (h0 = 0, pad cols 60..63 = 0) ----------
    for (int i = tid; i < 2 * BC * HPITCH; i += 1024)
        (&Hhi[0][0][0])[i] = 0;

    // ---------------- x fragment source: lane owns (row lm, k lk8..lk8+7) ---
    const float* xrow = x + (size_t)(b0 + lm) * (T_STEPS * F_IN) + lk8;
    float4 va0 = *reinterpret_cast<const float4*>(xrow);
    float4 vb0 = *reinterpret_cast<const float4*>(xrow + 4);
    short8 axh;
    CVTH(va0, vb0, axh)

    float cst = 0.f;                        // cell state for (b=lm, u=u4)
    const f32x4 z4 = {0.f, 0.f, 0.f, 0.f};
    __syncthreads();

// one LSTM step: x-frag from regs, h-frag (hi) from LDS[CUR], h -> LDS[NXT].
// TN = timestep whose x to prefetch for the NEXT step (must be < T_STEPS).
#define STEP(CUR, NXT, TT, TN)                                                  \
    {                                                                           \
        float4 nva = *reinterpret_cast<const float4*>(xrow + (TN) * F_IN);      \
        float4 nvb = *reinterpret_cast<const float4*>(xrow + (TN) * F_IN + 4);  \
        short8 uh1 = *reinterpret_cast<const short8*>(&Hhi[CUR][lm][lk8]);      \
        short8 uh2 = *reinterpret_cast<const short8*>(&Hhi[CUR][lm][32 + lk8]); \
        __builtin_amdgcn_s_setprio(1);                                          \
        f32x4 ph = MFMA(wh[0], axh, biasv);                                     \
        f32x4 pl = MFMA(wl[0], axh, z4);                                        \
        ph = MFMA(wh[1], uh1, ph);                                              \
        pl = MFMA(wl[1], uh1, pl);                                              \
        ph = MFMA(wh[2], uh2, ph);                                              \
        pl = MFMA(wl[2], uh2, pl);                                              \
        __builtin_amdgcn_s_setprio(0);                                          \
        if (mtok) {                                                             \
            float g0 = ph[0] + pl[0], g1 = ph[1] + pl[1];                       \
            float g2 = ph[2] + pl[2], g3 = ph[3] + pl[3];                       \
            float ig = sig2(g0), jg = tanh2(g1);                                \
            float fg = sig2(g2), og = sig2(g3);                                 \
            cst = cst * fg + ig * jg;                                           \
            float h = tanh2(cst * (2.0f * LOG2E)) * og;                         \
            int pk;                                                             \
            asm("v_cvt_pk_bf16_f32 %0, %1, %2" : "=v"(pk) : "v"(h), "v"(h));    \
            Hhi[NXT][lm][u4] = (short)pk;                                       \
            if ((TT) == T_STEPS - 1) Hf[lm][u4] = h;                            \
        }                                                                       \
        CVTH(nva, nvb, axh)                                                     \
        __syncthreads();                                                        \
    }

    for (int t = 0; t < T_STEPS - 2; t += 2) {
        STEP(0, 1, t, t + 1)
        STEP(1, 0, t + 1, t + 2)
    }
    STEP(0, 1, T_STEPS - 2, T_STEPS - 1)
    STEP(1, 0, T_STEPS - 1, T_STEPS - 1)    // final prefetch is a dummy reload

    // ---------------- epilogue: out[b] = h . dense_w + dense_b --------------
    if (tid < BC) {
        float acc = dense_b[0];
        #pragma unroll 4
        for (int uu = 0; uu < H_DIM; ++uu)
            acc = fmaf(Hf[tid][uu], dense_w[uu], acc);
        out[b0 + tid] = acc;
    }
}

extern "C" void kernel_launch(void* const* d_in, const int* in_sizes, int n_in,
                              void* d_out, int out_size, void* d_ws, size_t ws_size,
                              hipStream_t stream) {
    const float* x       = (const float*)d_in[0];
    const float* wk      = (const float*)d_in[1];
    const float* bias    = (const float*)d_in[2];
    const float* dense_w = (const float*)d_in[3];
    const float* dense_b = (const float*)d_in[4];
    float* out = (float*)d_out;

    lstm_mfma_kernel<<<B_TOTAL / BC, 1024, 0, stream>>>(
        x, wk, bias, dense_w, dense_b, out);
}

// Round 12
// 439.981 us; speedup vs baseline: 1.2454x; 1.2454x over previous
//
#include <hip/hip_runtime.h>

typedef short short8  __attribute__((ext_vector_type(8)));
typedef float f32x4   __attribute__((ext_vector_type(4)));

#define B_TOTAL 4096
#define T_STEPS 512
#define F_IN    32
#define H_DIM   60
#define KW      92      // F + H
#define BC      16      // batch rows per block
#define HPITCH  72      // h-LDS row pitch in halves (144B rows, 2-way-free)

#define MFMA(A, B, C) __builtin_amdgcn_mfma_f32_16x16x32_bf16((A), (B), (C), 0, 0, 0)

__device__ __forceinline__ unsigned short bf16rne(float f) {
    unsigned int u = __float_as_uint(f);
    u += 0x7FFFu + ((u >> 16) & 1u);
    return (unsigned short)(u >> 16);
}
__device__ __forceinline__ float bf16tof(unsigned short s) {
    return __uint_as_float(((unsigned int)s) << 16);
}
__device__ __forceinline__ float rcpf(float z) {
    return __builtin_amdgcn_rcpf(z);            // v_rcp_f32, 1 ulp
}
__device__ __forceinline__ float exp2f_(float z) {
#if __has_builtin(__builtin_amdgcn_exp2f)
    return __builtin_amdgcn_exp2f(z);           // v_exp_f32
#else
    float r; asm("v_exp_f32 %0, %1" : "=v"(r) : "v"(z)); return r;
#endif
}
// zs pre-scaled by log2e:
__device__ __forceinline__ float sig2(float zs) {      // sigmoid(z), zs=z*log2e
    return rcpf(1.0f + exp2f_(-zs));
}
// zs pre-scaled by 2*log2e:
__device__ __forceinline__ float tanh2(float zs) {     // tanh(z), zs=2z*log2e
    return fmaf(-2.0f, rcpf(1.0f + exp2f_(zs)), 1.0f);
}

// float4 pair -> packed bf16 short8 fragment, RNE, via v_cvt_pk_bf16_f32
#define CVTH(VA, VB, OH)                                                        \
    {                                                                           \
        int4 hp;                                                                \
        asm("v_cvt_pk_bf16_f32 %0, %1, %2" : "=v"(hp.x) : "v"((VA).x), "v"((VA).y)); \
        asm("v_cvt_pk_bf16_f32 %0, %1, %2" : "=v"(hp.y) : "v"((VA).z), "v"((VA).w)); \
        asm("v_cvt_pk_bf16_f32 %0, %1, %2" : "=v"(hp.z) : "v"((VB).x), "v"((VB).y)); \
        asm("v_cvt_pk_bf16_f32 %0, %1, %2" : "=v"(hp.w) : "v"((VB).z), "v"((VB).w)); \
        OH = __builtin_bit_cast(short8, hp);                                    \
    }

__global__ __launch_bounds__(512, 2)
void lstm_mfma_kernel(const float* __restrict__ x,
                      const float* __restrict__ wk,
                      const float* __restrict__ bias,
                      const float* __restrict__ dense_w,
                      const float* __restrict__ dense_b,
                      float* __restrict__ out)
{
    // Double-buffered h-state, bf16 hi plane only (weights carry the lo plane).
    __shared__ __align__(16) short Hhi[2][BC][HPITCH];
    __shared__ float Hf[BC][64];            // final-step h, f32, for epilogue

    const int tid  = threadIdx.x;
    const int lane = tid & 63;
    const int w    = tid >> 6;              // wave 0..7
    const int b0   = blockIdx.x * BC;
    const int lm   = lane & 15;             // batch row (B-operand N index)
    const int kg   = lane >> 4;             // K octet group 0..3
    const int lk8  = kg * 8;

    const float LOG2E = 1.44269504088896340736f;

    // ---------------- A fragments = W^T (static), exp2-prescaled, hi+lo -----
    // Wave w owns M-tiles 2w, 2w+1 (tile 15 = zero pad, skipped). D-layout:
    // lane (lm,kg) acc regs r=0..3 hold gates i,j,f,o (pre-scaled) of unit
    // u=4*mt+kg for batch row b=lm. Gate j scaled 2*log2e (tanh), others
    // log2e (sigmoid); forget +1 bias folded before scaling.
    short8 wh[2][3], wl[2][3];
    f32x4  biasv[2];
    #pragma unroll
    for (int tt = 0; tt < 2; ++tt) {
        const int mt = 2 * w + tt;
        if (mt < 15) {
            const int uo = 4 * mt + kg;
            f32x4 bv;
            #pragma unroll
            for (int r = 0; r < 4; ++r) {
                const float sc = (r == 1) ? 2.0f * LOG2E : LOG2E;
                bv[r] = (bias[r * 60 + uo] + (r == 2 ? 1.0f : 0.0f)) * sc;
            }
            biasv[tt] = bv;
            const int c = 16 * mt + lm;          // A-operand M-row
            const int u = c >> 2, g = c & 3;
            const float gsc = (g == 1) ? 2.0f * LOG2E : LOG2E;
            #pragma unroll
            for (int s = 0; s < 3; ++s) {
                short8 hv, lv;
                #pragma unroll
                for (int e = 0; e < 8; ++e) {
                    const int k = s * 32 + lk8 + e;
                    float wv = (k < KW) ? wk[k * 240 + g * 60 + u] * gsc : 0.0f;
                    unsigned short hh = bf16rne(wv);
                    hv[e] = (short)hh;
                    lv[e] = (short)bf16rne(wv - bf16tof(hh));
                }
                wh[tt][s] = hv;
                wl[tt][s] = lv;
            }
        } else {
            biasv[tt] = (f32x4){0.f, 0.f, 0.f, 0.f};
            #pragma unroll
            for (int s = 0; s < 3; ++s) { wh[tt][s] = (short8)0; wl[tt][s] = (short8)0; }
        }
    }
    const int u0 = 8 * w + kg;              // unit of tile mt0 output
    const int u1 = 8 * w + 4 + kg;          // unit of tile mt1 output
    const bool t1ok = (2 * w + 1 < 15);

    // ---------------- zero h buffers (h0 = 0, pad cols 60..63 = 0) ----------
    for (int i = tid; i < 2 * BC * HPITCH; i += 512)
        (&Hhi[0][0][0])[i] = 0;

    // ---------------- x fragment source: lane owns (row lm, k lk8..lk8+7) ---
    const float* xrow = x + (size_t)(b0 + lm) * (T_STEPS * F_IN) + lk8;
    float4 va0 = *reinterpret_cast<const float4*>(xrow);
    float4 vb0 = *reinterpret_cast<const float4*>(xrow + 4);
    short8 axh;
    CVTH(va0, vb0, axh)

    // pre-barrier x-partials for step 0 (2-link chain heads)
    f32x4 xp, xq = {0.f, 0.f, 0.f, 0.f};
    xp = MFMA(wh[0][0], axh, biasv[0]);
    xp = MFMA(wl[0][0], axh, xp);
    if (t1ok) {
        xq = MFMA(wh[1][0], axh, biasv[1]);
        xq = MFMA(wl[1][0], axh, xq);
    }

    float cst0 = 0.f, cst1 = 0.f;           // cell state for (b=lm, u0/u1)
    __syncthreads();                        // h-zero visible; step 0 begins

// one LSTM step. Entering: xp/xq hold the x-contribution 2-link partials for
// this step; axh holds x(this step). TN = x time index to prefetch for the
// NEXT step. Exits with xp/xq/axh advanced and barrier passed.
#define STEP(CUR, NXT, TN, LAST)                                                \
    {                                                                           \
        short8 uh1 = *reinterpret_cast<const short8*>(&Hhi[CUR][lm][lk8]);      \
        short8 uh2 = *reinterpret_cast<const short8*>(&Hhi[CUR][lm][32 + lk8]); \
        float4 nva = *reinterpret_cast<const float4*>(xrow + (TN) * F_IN);      \
        float4 nvb = *reinterpret_cast<const float4*>(xrow + (TN) * F_IN + 4);  \
        __builtin_amdgcn_s_setprio(1);                                          \
        f32x4 p = MFMA(wh[0][1], uh1, xp);                                      \
        p = MFMA(wl[0][1], uh1, p);                                             \
        p = MFMA(wh[0][2], uh2, p);                                             \
        p = MFMA(wl[0][2], uh2, p);                                             \
        f32x4 q = xq;                                                           \
        if (t1ok) {                                                             \
            q = MFMA(wh[1][1], uh1, xq);                                        \
            q = MFMA(wl[1][1], uh1, q);                                         \
            q = MFMA(wh[1][2], uh2, q);                                         \
            q = MFMA(wl[1][2], uh2, q);                                         \
        }                                                                       \
        __builtin_amdgcn_s_setprio(0);                                          \
        {                                                                       \
            float ig = sig2(p[0]), jg = tanh2(p[1]);                            \
            float fg = sig2(p[2]), og = sig2(p[3]);                             \
            cst0 = cst0 * fg + ig * jg;                                         \
            float h = tanh2(cst0 * (2.0f * LOG2E)) * og;                        \
            if (LAST) { Hf[lm][u0] = h; }                                       \
            else {                                                              \
                int pk;                                                         \
                asm("v_cvt_pk_bf16_f32 %0, %1, %2" : "=v"(pk) : "v"(h), "v"(h));\
                Hhi[NXT][lm][u0] = (short)pk;                                   \
            }                                                                   \
        }                                                                       \
        if (t1ok) {                                                             \
            float ig = sig2(q[0]), jg = tanh2(q[1]);                            \
            float fg = sig2(q[2]), og = sig2(q[3]);                             \
            cst1 = cst1 * fg + ig * jg;                                         \
            float h = tanh2(cst1 * (2.0f * LOG2E)) * og;                        \
            if (LAST) { Hf[lm][u1] = h; }                                       \
            else {                                                              \
                int pk;                                                         \
                asm("v_cvt_pk_bf16_f32 %0, %1, %2" : "=v"(pk) : "v"(h), "v"(h));\
                Hhi[NXT][lm][u1] = (short)pk;                                   \
            }                                                                   \
        }                                                                       \
        if (!(LAST)) {                                                          \
            CVTH(nva, nvb, axh)                                                 \
            xp = MFMA(wh[0][0], axh, biasv[0]);                                 \
            xp = MFMA(wl[0][0], axh, xp);                                       \
            if (t1ok) {                                                         \
                xq = MFMA(wh[1][0], axh, biasv[1]);                             \
                xq = MFMA(wl[1][0], axh, xq);                                   \
            }                                                                   \
        }                                                                       \
        __syncthreads();                                                        \
    }

    for (int t = 0; t < T_STEPS - 2; t += 2) {
        STEP(0, 1, t + 1, 0)
        STEP(1, 0, t + 2, 0)
    }
    STEP(0, 1, T_STEPS - 1, 0)      // step 510
    STEP(1, 0, T_STEPS - 1, 1)      // step 511 (writes Hf; dummy prefetch idx)

    // ---------------- epilogue: out[b] = h . dense_w + dense_b --------------
    if (tid < BC) {
        float acc = dense_b[0];
        #pragma unroll 4
        for (int uu = 0; uu < H_DIM; ++uu)
            acc = fmaf(Hf[tid][uu], dense_w[uu], acc);
        out[b0 + tid] = acc;
    }
}

extern "C" void kernel_launch(void* const* d_in, const int* in_sizes, int n_in,
                              void* d_out, int out_size, void* d_ws, size_t ws_size,
                              hipStream_t stream) {
    const float* x       = (const float*)d_in[0];
    const float* wk      = (const float*)d_in[1];
    const float* bias    = (const float*)d_in[2];
    const float* dense_w = (const float*)d_in[3];
    const float* dense_b = (const float*)d_in[4];
    float* out = (float*)d_out;

    lstm_mfma_kernel<<<B_TOTAL / BC, 512, 0, stream>>>(
        x, wk, bias, dense_w, dense_b, out);
}

// Round 13
// 334.719 us; speedup vs baseline: 1.6371x; 1.3145x over previous
//
#include <hip/hip_runtime.h>

typedef short short8  __attribute__((ext_vector_type(8)));
typedef float f32x4   __attribute__((ext_vector_type(4)));

#define B_TOTAL 4096
#define T_STEPS 512
#define F_IN    32
#define H_DIM   60
#define KW      92      // F + H
#define BC      16      // batch rows per block
#define HPITCH  72      // h-LDS row pitch in halves (144B rows, 2-way-free)

#define MFMA(A, B, C) __builtin_amdgcn_mfma_f32_16x16x32_bf16((A), (B), (C), 0, 0, 0)

__device__ __forceinline__ unsigned short bf16rne(float f) {
    unsigned int u = __float_as_uint(f);
    u += 0x7FFFu + ((u >> 16) & 1u);
    return (unsigned short)(u >> 16);
}
__device__ __forceinline__ float bf16tof(unsigned short s) {
    return __uint_as_float(((unsigned int)s) << 16);
}
__device__ __forceinline__ float rcpf(float z) {
    return __builtin_amdgcn_rcpf(z);            // v_rcp_f32, 1 ulp
}
__device__ __forceinline__ float exp2f_(float z) {
#if __has_builtin(__builtin_amdgcn_exp2f)
    return __builtin_amdgcn_exp2f(z);           // v_exp_f32
#else
    float r; asm("v_exp_f32 %0, %1" : "=v"(r) : "v"(z)); return r;
#endif
}

// float4 pair -> packed bf16 short8 fragment, RNE, via v_cvt_pk_bf16_f32
#define CVTH(VA, VB, OH)                                                        \
    {                                                                           \
        int4 hp;                                                                \
        asm("v_cvt_pk_bf16_f32 %0, %1, %2" : "=v"(hp.x) : "v"((VA).x), "v"((VA).y)); \
        asm("v_cvt_pk_bf16_f32 %0, %1, %2" : "=v"(hp.y) : "v"((VA).z), "v"((VA).w)); \
        asm("v_cvt_pk_bf16_f32 %0, %1, %2" : "=v"(hp.z) : "v"((VB).x), "v"((VB).y)); \
        asm("v_cvt_pk_bf16_f32 %0, %1, %2" : "=v"(hp.w) : "v"((VB).z), "v"((VB).w)); \
        OH = __builtin_bit_cast(short8, hp);                                    \
    }

// Fused LSTM cell update. g0..g3 = i,j,f,o pre-activations, pre-scaled:
// i,f,o by log2e; j by 2*log2e; forget +1 bias already folded.
// Uses 5 exp2 + 3 rcp (vs 10 trans naive).
#define CELL(G0, G1, G2, G3, CST, H)                                            \
    {                                                                           \
        float ei = exp2f_(-(G0));                                               \
        float qj = exp2f_((G1));                                                \
        float ef = exp2f_(-(G2));                                               \
        float prod = (qj - 1.0f) * rcpf((1.0f + ei) * (qj + 1.0f));             \
        float fg = rcpf(1.0f + ef);                                             \
        CST = CST * fg + prod;                                                  \
        float zc = fminf(fmaxf(CST * (2.0f * 1.44269504088896340736f), -126.f), 126.f); \
        float qc = exp2f_(zc);                                                  \
        float eo = exp2f_(-(G3));                                               \
        H = (qc - 1.0f) * rcpf((qc + 1.0f) * (1.0f + eo));                      \
    }

__global__ __launch_bounds__(512, 2)
void lstm_mfma_kernel(const float* __restrict__ x,
                      const float* __restrict__ wk,
                      const float* __restrict__ bias,
                      const float* __restrict__ dense_w,
                      const float* __restrict__ dense_b,
                      float* __restrict__ out)
{
    // Double-buffered h-state, bf16 hi plane only (weights carry the lo plane).
    __shared__ __align__(16) short Hhi[2][BC][HPITCH];
    __shared__ float Hf[BC][64];            // final-step h, f32, for epilogue

    const int tid  = threadIdx.x;
    const int lane = tid & 63;
    const int w    = tid >> 6;              // wave 0..7
    const int b0   = blockIdx.x * BC;
    const int lm   = lane & 15;             // batch row (B-operand N index)
    const int kg   = lane >> 4;             // K octet group 0..3
    const int lk8  = kg * 8;

    const float LOG2E = 1.44269504088896340736f;

    // ---------------- A fragments = W^T (static), exp2-prescaled, hi+lo -----
    // Wave w owns M-tiles 2w, 2w+1 (tile 15 = zero pad). D-layout: lane
    // (lm,kg) acc regs r=0..3 hold gates i,j,f,o (pre-scaled) of unit
    // u=4*mt+kg for batch row b=lm. Gate j scaled 2*log2e (tanh), others
    // log2e (sigmoid); forget +1 bias folded before scaling.
    short8 wh[2][3], wl[2][3];
    f32x4  biasv[2];
    #pragma unroll
    for (int tt = 0; tt < 2; ++tt) {
        const int mt = 2 * w + tt;
        if (mt < 15) {
            const int uo = 4 * mt + kg;
            f32x4 bv;
            #pragma unroll
            for (int r = 0; r < 4; ++r) {
                const float sc = (r == 1) ? 2.0f * LOG2E : LOG2E;
                bv[r] = (bias[r * 60 + uo] + (r == 2 ? 1.0f : 0.0f)) * sc;
            }
            biasv[tt] = bv;
            const int c = 16 * mt + lm;          // A-operand M-row
            const int u = c >> 2, g = c & 3;
            const float gsc = (g == 1) ? 2.0f * LOG2E : LOG2E;
            #pragma unroll
            for (int s = 0; s < 3; ++s) {
                short8 hv, lv;
                #pragma unroll
                for (int e = 0; e < 8; ++e) {
                    const int k = s * 32 + lk8 + e;
                    float wv = (k < KW) ? wk[k * 240 + g * 60 + u] * gsc : 0.0f;
                    unsigned short hh = bf16rne(wv);
                    hv[e] = (short)hh;
                    lv[e] = (short)bf16rne(wv - bf16tof(hh));
                }
                wh[tt][s] = hv;
                wl[tt][s] = lv;
            }
        } else {
            biasv[tt] = (f32x4){0.f, 0.f, 0.f, 0.f};
            #pragma unroll
            for (int s = 0; s < 3; ++s) { wh[tt][s] = (short8)0; wl[tt][s] = (short8)0; }
        }
    }
    const int u0 = 8 * w + kg;              // unit of tile mt0 output
    const int u1 = 8 * w + 4 + kg;          // unit of tile mt1 output
    const bool t1ok = (2 * w + 1 < 15);

    // ---------------- zero h buffers (h0 = 0, pad cols 60..63 = 0) ----------
    for (int i = tid; i < 2 * BC * HPITCH; i += 512)
        (&Hhi[0][0][0])[i] = 0;

    // ---------------- x fragment source: lane owns (row lm, k lk8..lk8+7) ---
    const float* xrow = x + (size_t)(b0 + lm) * (T_STEPS * F_IN) + lk8;
    float4 va0 = *reinterpret_cast<const float4*>(xrow);
    float4 vb0 = *reinterpret_cast<const float4*>(xrow + 4);
    short8 axh;
    CVTH(va0, vb0, axh)

    float cst0 = 0.f, cst1 = 0.f;           // cell state for (b=lm, u0/u1)
    const f32x4 z4 = {0.f, 0.f, 0.f, 0.f};
    __syncthreads();

// one LSTM step: x-frag from regs, h-frag (hi) from LDS[CUR], h -> LDS[NXT].
// 4 independent 3-deep MFMA chains; first links are x-only (cover ds latency).
#define STEP(CUR, NXT, TT)                                                      \
    {                                                                           \
        short8 uh1 = *reinterpret_cast<const short8*>(&Hhi[CUR][lm][lk8]);      \
        short8 uh2 = *reinterpret_cast<const short8*>(&Hhi[CUR][lm][32 + lk8]); \
        const int tn = ((TT) + 1 < T_STEPS) ? (TT) + 1 : (TT);                  \
        float4 nva = *reinterpret_cast<const float4*>(xrow + tn * F_IN);        \
        float4 nvb = *reinterpret_cast<const float4*>(xrow + tn * F_IN + 4);    \
        __builtin_amdgcn_s_setprio(1);                                          \
        f32x4 ph = MFMA(wh[0][0], axh, biasv[0]);                               \
        f32x4 pl = MFMA(wl[0][0], axh, z4);                                     \
        f32x4 qh = MFMA(wh[1][0], axh, biasv[1]);                               \
        f32x4 ql = MFMA(wl[1][0], axh, z4);                                     \
        ph = MFMA(wh[0][1], uh1, ph);                                           \
        pl = MFMA(wl[0][1], uh1, pl);                                           \
        qh = MFMA(wh[1][1], uh1, qh);                                           \
        ql = MFMA(wl[1][1], uh1, ql);                                           \
        ph = MFMA(wh[0][2], uh2, ph);                                           \
        pl = MFMA(wl[0][2], uh2, pl);                                           \
        qh = MFMA(wh[1][2], uh2, qh);                                           \
        ql = MFMA(wl[1][2], uh2, ql);                                           \
        __builtin_amdgcn_s_setprio(0);                                          \
        {                                                                       \
            float g0 = ph[0] + pl[0], g1 = ph[1] + pl[1];                       \
            float g2 = ph[2] + pl[2], g3 = ph[3] + pl[3];                       \
            float h;                                                            \
            CELL(g0, g1, g2, g3, cst0, h)                                       \
            int pk;                                                             \
            asm("v_cvt_pk_bf16_f32 %0, %1, %2" : "=v"(pk) : "v"(h), "v"(h));    \
            Hhi[NXT][lm][u0] = (short)pk;                                       \
            if ((TT) == T_STEPS - 1) Hf[lm][u0] = h;                            \
        }                                                                       \
        if (t1ok) {                                                             \
            float g0 = qh[0] + ql[0], g1 = qh[1] + ql[1];                       \
            float g2 = qh[2] + ql[2], g3 = qh[3] + ql[3];                       \
            float h;                                                            \
            CELL(g0, g1, g2, g3, cst1, h)                                       \
            int pk;                                                             \
            asm("v_cvt_pk_bf16_f32 %0, %1, %2" : "=v"(pk) : "v"(h), "v"(h));    \
            Hhi[NXT][lm][u1] = (short)pk;                                       \
            if ((TT) == T_STEPS - 1) Hf[lm][u1] = h;                            \
        }                                                                       \
        CVTH(nva, nvb, axh)                                                     \
        __syncthreads();                                                        \
    }

    for (int t = 0; t < T_STEPS; t += 2) {
        STEP(0, 1, t)
        STEP(1, 0, t + 1)
    }

    // ---------------- epilogue: out[b] = h . dense_w + dense_b --------------
    if (tid < BC) {
        float acc = dense_b[0];
        #pragma unroll 4
        for (int uu = 0; uu < H_DIM; ++uu)
            acc = fmaf(Hf[tid][uu], dense_w[uu], acc);
        out[b0 + tid] = acc;
    }
}

extern "C" void kernel_launch(void* const* d_in, const int* in_sizes, int n_in,
                              void* d_out, int out_size, void* d_ws, size_t ws_size,
                              hipStream_t stream) {
    const float* x       = (const float*)d_in[0];
    const float* wk      = (const float*)d_in[1];
    const float* bias    = (const float*)d_in[2];
    const float* dense_w = (const float*)d_in[3];
    const float* dense_b = (const float*)d_in[4];
    float* out = (float*)d_out;

    lstm_mfma_kernel<<<B_TOTAL / BC, 512, 0, stream>>>(
        x, wk, bias, dense_w, dense_b, out);
}

// Round 14
// 271.416 us; speedup vs baseline: 2.0189x; 1.2332x over previous
//
#include <hip/hip_runtime.h>

typedef short short8  __attribute__((ext_vector_type(8)));
typedef float f32x4   __attribute__((ext_vector_type(4)));

#define B_TOTAL 4096
#define T_STEPS 512
#define F_IN    32
#define H_DIM   60
#define KW      92      // F + H
#define BC      16      // batch rows per block
#define HPITCH  72      // h-LDS row pitch in halves (144B rows, 2-way-free)

#define MFMA(A, B, C) __builtin_amdgcn_mfma_f32_16x16x32_bf16((A), (B), (C), 0, 0, 0)

__device__ __forceinline__ unsigned short bf16rne(float f) {
    unsigned int u = __float_as_uint(f);
    u += 0x7FFFu + ((u >> 16) & 1u);
    return (unsigned short)(u >> 16);
}
__device__ __forceinline__ float bf16tof(unsigned short s) {
    return __uint_as_float(((unsigned int)s) << 16);
}
__device__ __forceinline__ float rcpf(float z) {
    return __builtin_amdgcn_rcpf(z);            // v_rcp_f32, 1 ulp
}
__device__ __forceinline__ float exp2f_(float z) {
#if __has_builtin(__builtin_amdgcn_exp2f)
    return __builtin_amdgcn_exp2f(z);           // v_exp_f32
#else
    float r; asm("v_exp_f32 %0, %1" : "=v"(r) : "v"(z)); return r;
#endif
}

// LDS-visibility barrier WITHOUT the vmcnt(0) drain __syncthreads() imposes:
// outstanding global loads (x prefetch) stay in flight across it.
#define BAR()                                                                   \
    {                                                                           \
        asm volatile("s_waitcnt lgkmcnt(0)" ::: "memory");                      \
        __builtin_amdgcn_sched_barrier(0);                                      \
        __builtin_amdgcn_s_barrier();                                           \
        __builtin_amdgcn_sched_barrier(0);                                      \
    }

// float4 pair -> packed bf16 short8 fragment, RNE, via v_cvt_pk_bf16_f32
#define CVTH(VA, VB, OH)                                                        \
    {                                                                           \
        int4 hp;                                                                \
        asm("v_cvt_pk_bf16_f32 %0, %1, %2" : "=v"(hp.x) : "v"((VA).x), "v"((VA).y)); \
        asm("v_cvt_pk_bf16_f32 %0, %1, %2" : "=v"(hp.y) : "v"((VA).z), "v"((VA).w)); \
        asm("v_cvt_pk_bf16_f32 %0, %1, %2" : "=v"(hp.z) : "v"((VB).x), "v"((VB).y)); \
        asm("v_cvt_pk_bf16_f32 %0, %1, %2" : "=v"(hp.w) : "v"((VB).z), "v"((VB).w)); \
        OH = __builtin_bit_cast(short8, hp);                                    \
    }

// Fused LSTM cell update. g0..g3 = i,j,f,o pre-activations, pre-scaled:
// i,f,o by log2e; j by 2*log2e; forget +1 bias already folded.
#define CELL(G0, G1, G2, G3, CST, H)                                            \
    {                                                                           \
        float ei = exp2f_(-(G0));                                               \
        float qj = exp2f_((G1));                                                \
        float ef = exp2f_(-(G2));                                               \
        float prod = (qj - 1.0f) * rcpf((1.0f + ei) * (qj + 1.0f));             \
        float fg = rcpf(1.0f + ef);                                             \
        CST = CST * fg + prod;                                                  \
        float zc = fminf(fmaxf(CST * (2.0f * 1.44269504088896340736f), -126.f), 126.f); \
        float qc = exp2f_(zc);                                                  \
        float eo = exp2f_(-(G3));                                               \
        H = (qc - 1.0f) * rcpf((qc + 1.0f) * (1.0f + eo));                      \
    }

__global__ __launch_bounds__(512, 2)
void lstm_mfma_kernel(const float* __restrict__ x,
                      const float* __restrict__ wk,
                      const float* __restrict__ bias,
                      const float* __restrict__ dense_w,
                      const float* __restrict__ dense_b,
                      float* __restrict__ out)
{
    // Double-buffered h-state, bf16 hi plane only (weights carry the lo plane).
    __shared__ __align__(16) short Hhi[2][BC][HPITCH];
    __shared__ float Hf[BC][64];            // final-step h, f32, for epilogue

    const int tid  = threadIdx.x;
    const int lane = tid & 63;
    const int w    = tid >> 6;              // wave 0..7
    const int b0   = blockIdx.x * BC;
    const int lm   = lane & 15;             // batch row (B-operand N index)
    const int kg   = lane >> 4;             // K octet group 0..3
    const int lk8  = kg * 8;

    const float LOG2E = 1.44269504088896340736f;

    // ---------------- A fragments = W^T (static), exp2-prescaled, hi+lo -----
    // Wave w owns M-tiles 2w, 2w+1 (tile 15 = zero pad). D-layout: lane
    // (lm,kg) acc regs r=0..3 hold gates i,j,f,o (pre-scaled) of unit
    // u=4*mt+kg for batch row b=lm. Gate j scaled 2*log2e (tanh), others
    // log2e (sigmoid); forget +1 bias folded before scaling.
    short8 wh[2][3], wl[2][3];
    f32x4  biasv[2];
    #pragma unroll
    for (int tt = 0; tt < 2; ++tt) {
        const int mt = 2 * w + tt;
        if (mt < 15) {
            const int uo = 4 * mt + kg;
            f32x4 bv;
            #pragma unroll
            for (int r = 0; r < 4; ++r) {
                const float sc = (r == 1) ? 2.0f * LOG2E : LOG2E;
                bv[r] = (bias[r * 60 + uo] + (r == 2 ? 1.0f : 0.0f)) * sc;
            }
            biasv[tt] = bv;
            const int c = 16 * mt + lm;          // A-operand M-row
            const int u = c >> 2, g = c & 3;
            const float gsc = (g == 1) ? 2.0f * LOG2E : LOG2E;
            #pragma unroll
            for (int s = 0; s < 3; ++s) {
                short8 hv, lv;
                #pragma unroll
                for (int e = 0; e < 8; ++e) {
                    const int k = s * 32 + lk8 + e;
                    float wv = (k < KW) ? wk[k * 240 + g * 60 + u] * gsc : 0.0f;
                    unsigned short hh = bf16rne(wv);
                    hv[e] = (short)hh;
                    lv[e] = (short)bf16rne(wv - bf16tof(hh));
                }
                wh[tt][s] = hv;
                wl[tt][s] = lv;
            }
        } else {
            biasv[tt] = (f32x4){0.f, 0.f, 0.f, 0.f};
            #pragma unroll
            for (int s = 0; s < 3; ++s) { wh[tt][s] = (short8)0; wl[tt][s] = (short8)0; }
        }
    }
    const int u0 = 8 * w + kg;              // unit of tile mt0 output
    const int u1 = 8 * w + 4 + kg;          // unit of tile mt1 output
    const bool t1ok = (2 * w + 1 < 15);

    // ---------------- zero h buffers (h0 = 0, pad cols 60..63 = 0) ----------
    for (int i = tid; i < 2 * BC * HPITCH; i += 512)
        (&Hhi[0][0][0])[i] = 0;

    // ---------------- x fragments: lane owns (row lm, k lk8..lk8+7) ---------
    const float* xrow = x + (size_t)(b0 + lm) * (T_STEPS * F_IN) + lk8;
    float4 va0 = *reinterpret_cast<const float4*>(xrow);
    float4 vb0 = *reinterpret_cast<const float4*>(xrow + 4);
    short8 axh;
    CVTH(va0, vb0, axh)
    // prefetch slot B <- x(1); slot A is filled in-loop with x(t+2)
    float4 sBa = *reinterpret_cast<const float4*>(xrow + 1 * F_IN);
    float4 sBb = *reinterpret_cast<const float4*>(xrow + 1 * F_IN + 4);
    float4 sAa, sAb;

    float cst0 = 0.f, cst1 = 0.f;           // cell state for (b=lm, u0/u1)
    const f32x4 z4 = {0.f, 0.f, 0.f, 0.f};
    __syncthreads();

// one LSTM step. Issues load of x(TT+2) into slot L*, converts slot C*
// (holding x(TT+1)) into axh at the end. Raw barrier: lgkm only, vmcnt
// stays outstanding -> 2 x-loads in flight across barriers.
#define STEP(CUR, NXT, TT, LA, LB, CA, CB)                                      \
    {                                                                           \
        const int tn2 = ((TT) + 2 < T_STEPS) ? (TT) + 2 : T_STEPS - 1;          \
        LA = *reinterpret_cast<const float4*>(xrow + tn2 * F_IN);               \
        LB = *reinterpret_cast<const float4*>(xrow + tn2 * F_IN + 4);           \
        short8 uh1 = *reinterpret_cast<const short8*>(&Hhi[CUR][lm][lk8]);      \
        short8 uh2 = *reinterpret_cast<const short8*>(&Hhi[CUR][lm][32 + lk8]); \
        __builtin_amdgcn_s_setprio(1);                                          \
        f32x4 ph = MFMA(wh[0][0], axh, biasv[0]);                               \
        f32x4 pl = MFMA(wl[0][0], axh, z4);                                     \
        f32x4 qh = MFMA(wh[1][0], axh, biasv[1]);                               \
        f32x4 ql = MFMA(wl[1][0], axh, z4);                                     \
        ph = MFMA(wh[0][1], uh1, ph);                                           \
        pl = MFMA(wl[0][1], uh1, pl);                                           \
        qh = MFMA(wh[1][1], uh1, qh);                                           \
        ql = MFMA(wl[1][1], uh1, ql);                                           \
        ph = MFMA(wh[0][2], uh2, ph);                                           \
        pl = MFMA(wl[0][2], uh2, pl);                                           \
        qh = MFMA(wh[1][2], uh2, qh);                                           \
        ql = MFMA(wl[1][2], uh2, ql);                                           \
        __builtin_amdgcn_s_setprio(0);                                          \
        {                                                                       \
            float g0 = ph[0] + pl[0], g1 = ph[1] + pl[1];                       \
            float g2 = ph[2] + pl[2], g3 = ph[3] + pl[3];                       \
            float h;                                                            \
            CELL(g0, g1, g2, g3, cst0, h)                                       \
            int pk;                                                             \
            asm("v_cvt_pk_bf16_f32 %0, %1, %2" : "=v"(pk) : "v"(h), "v"(h));    \
            Hhi[NXT][lm][u0] = (short)pk;                                       \
            if ((TT) == T_STEPS - 1) Hf[lm][u0] = h;                            \
        }                                                                       \
        if (t1ok) {                                                             \
            float g0 = qh[0] + ql[0], g1 = qh[1] + ql[1];                       \
            float g2 = qh[2] + ql[2], g3 = qh[3] + ql[3];                       \
            float h;                                                            \
            CELL(g0, g1, g2, g3, cst1, h)                                       \
            int pk;                                                             \
            asm("v_cvt_pk_bf16_f32 %0, %1, %2" : "=v"(pk) : "v"(h), "v"(h));    \
            Hhi[NXT][lm][u1] = (short)pk;                                       \
            if ((TT) == T_STEPS - 1) Hf[lm][u1] = h;                            \
        }                                                                       \
        CVTH(CA, CB, axh)                                                       \
        BAR()                                                                   \
    }

    for (int t = 0; t < T_STEPS; t += 2) {
        STEP(0, 1, t,     sAa, sAb, sBa, sBb)   // load x(t+2)->A, cvt x(t+1) from B
        STEP(1, 0, t + 1, sBa, sBb, sAa, sAb)   // load x(t+3)->B, cvt x(t+2) from A
    }

    // ---------------- epilogue: out[b] = h . dense_w + dense_b --------------
    if (tid < BC) {
        float acc = dense_b[0];
        #pragma unroll 4
        for (int uu = 0; uu < H_DIM; ++uu)
            acc = fmaf(Hf[tid][uu], dense_w[uu], acc);
        out[b0 + tid] = acc;
    }
}

extern "C" void kernel_launch(void* const* d_in, const int* in_sizes, int n_in,
                              void* d_out, int out_size, void* d_ws, size_t ws_size,
                              hipStream_t stream) {
    const float* x       = (const float*)d_in[0];
    const float* wk      = (const float*)d_in[1];
    const float* bias    = (const float*)d_in[2];
    const float* dense_w = (const float*)d_in[3];
    const float* dense_b = (const float*)d_in[4];
    float* out = (float*)d_out;

    lstm_mfma_kernel<<<B_TOTAL / BC, 512, 0, stream>>>(
        x, wk, bias, dense_w, dense_b, out);
}

// Round 15
// 238.907 us; speedup vs baseline: 2.2936x; 1.1361x over previous
//
#include <hip/hip_runtime.h>

typedef short short8  __attribute__((ext_vector_type(8)));
typedef float f32x4   __attribute__((ext_vector_type(4)));

#define B_TOTAL 4096
#define T_STEPS 512
#define F_IN    32
#define H_DIM   60
#define KW      92      // F + H
#define BC      16      // batch rows per block
#define HPITCH  72      // h-LDS row pitch in halves (144B rows, 2-way-free)

#define MFMA(A, B, C) __builtin_amdgcn_mfma_f32_16x16x32_bf16((A), (B), (C), 0, 0, 0)

__device__ __forceinline__ unsigned short bf16rne(float f) {
    unsigned int u = __float_as_uint(f);
    u += 0x7FFFu + ((u >> 16) & 1u);
    return (unsigned short)(u >> 16);
}
__device__ __forceinline__ float bf16tof(unsigned short s) {
    return __uint_as_float(((unsigned int)s) << 16);
}
__device__ __forceinline__ float rcpf(float z) {
    return __builtin_amdgcn_rcpf(z);            // v_rcp_f32, 1 ulp
}
__device__ __forceinline__ float exp2f_(float z) {
#if __has_builtin(__builtin_amdgcn_exp2f)
    return __builtin_amdgcn_exp2f(z);           // v_exp_f32
#else
    float r; asm("v_exp_f32 %0, %1" : "=v"(r) : "v"(z)); return r;
#endif
}

// LDS-visibility barrier WITHOUT the vmcnt(0) drain __syncthreads() imposes:
// outstanding global loads (x prefetch) stay in flight across it.
#define BAR()                                                                   \
    {                                                                           \
        asm volatile("s_waitcnt lgkmcnt(0)" ::: "memory");                      \
        __builtin_amdgcn_sched_barrier(0);                                      \
        __builtin_amdgcn_s_barrier();                                           \
        __builtin_amdgcn_sched_barrier(0);                                      \
    }

// float4 pair -> packed bf16 short8 fragment, RNE, via v_cvt_pk_bf16_f32
#define CVTH(VA, VB, OH)                                                        \
    {                                                                           \
        int4 hp;                                                                \
        asm("v_cvt_pk_bf16_f32 %0, %1, %2" : "=v"(hp.x) : "v"((VA).x), "v"((VA).y)); \
        asm("v_cvt_pk_bf16_f32 %0, %1, %2" : "=v"(hp.y) : "v"((VA).z), "v"((VA).w)); \
        asm("v_cvt_pk_bf16_f32 %0, %1, %2" : "=v"(hp.z) : "v"((VB).x), "v"((VB).y)); \
        asm("v_cvt_pk_bf16_f32 %0, %1, %2" : "=v"(hp.w) : "v"((VB).z), "v"((VB).w)); \
        OH = __builtin_bit_cast(short8, hp);                                    \
    }

// Paired LSTM cell update for units u0 (gates P) and u1 (gates Q).
// Pre-activations pre-scaled: i,f,o by log2e; j by 2*log2e; forget +1 folded.
// D1/D2 reciprocals merged across the pair (products bounded < 2^60);
// D3 kept per-unit (qc can reach 2^126 after clamp -> merge would overflow).
#define CELL2(P, Q, H0, H1)                                                     \
    float h0, h1;                                                               \
    {                                                                           \
        float ei0 = exp2f_(-P[0]), ei1 = exp2f_(-Q[0]);                         \
        float qj0 = exp2f_(P[1]),  qj1 = exp2f_(Q[1]);                          \
        float ef0 = exp2f_(-P[2]), ef1 = exp2f_(-Q[2]);                         \
        float D10 = (1.0f + ei0) * (qj0 + 1.0f);                                \
        float D11 = (1.0f + ei1) * (qj1 + 1.0f);                                \
        float r1  = rcpf(D10 * D11);                                            \
        float D20 = 1.0f + ef0, D21 = 1.0f + ef1;                               \
        float r2  = rcpf(D20 * D21);                                            \
        cst0 = cst0 * (D21 * r2) + (qj0 - 1.0f) * (D11 * r1);                   \
        cst1 = cst1 * (D20 * r2) + (qj1 - 1.0f) * (D10 * r1);                   \
        float zc0 = __builtin_amdgcn_fmed3f(cst0 * (2.0f * 1.44269504088896340736f), -126.0f, 126.0f); \
        float zc1 = __builtin_amdgcn_fmed3f(cst1 * (2.0f * 1.44269504088896340736f), -126.0f, 126.0f); \
        float qc0 = exp2f_(zc0), qc1 = exp2f_(zc1);                             \
        float eo0 = exp2f_(-P[3]), eo1 = exp2f_(-Q[3]);                         \
        H0 = (qc0 - 1.0f) * rcpf((qc0 + 1.0f) * (1.0f + eo0));                  \
        H1 = (qc1 - 1.0f) * rcpf((qc1 + 1.0f) * (1.0f + eo1));                  \
    }

__global__ __launch_bounds__(512, 2)
void lstm_mfma_kernel(const float* __restrict__ x,
                      const float* __restrict__ wk,
                      const float* __restrict__ bias,
                      const float* __restrict__ dense_w,
                      const float* __restrict__ dense_b,
                      float* __restrict__ out)
{
    // Double-buffered h-state, bf16 hi plane only (weights carry the lo plane).
    __shared__ __align__(16) short Hhi[2][BC][HPITCH];
    __shared__ float Hf[BC][64];            // final-step h, f32, for epilogue

    const int tid  = threadIdx.x;
    const int lane = tid & 63;
    const int w    = tid >> 6;              // wave 0..7
    const int b0   = blockIdx.x * BC;
    const int lm   = lane & 15;             // batch row (B-operand N index)
    const int kg   = lane >> 4;             // K octet group 0..3
    const int lk8  = kg * 8;

    const float LOG2E = 1.44269504088896340736f;

    // ---------------- A fragments = W^T (static), exp2-prescaled ------------
    // Wave w owns M-tiles 2w, 2w+1 (tile 15 = zero pad). D-layout: lane
    // (lm,kg) acc regs r=0..3 hold gates i,j,f,o (pre-scaled) of unit
    // u=4*mt+kg for batch row b=lm. Gate j scaled 2*log2e (tanh), others
    // log2e (sigmoid); forget +1 bias folded. hi+lo planes for the h K-steps
    // (s=1,2); x K-step (s=0) uses the hi plane only.
    short8 wh[2][3], wl[2][3];
    f32x4  biasv[2];
    #pragma unroll
    for (int tt = 0; tt < 2; ++tt) {
        const int mt = 2 * w + tt;
        if (mt < 15) {
            const int uo = 4 * mt + kg;
            f32x4 bv;
            #pragma unroll
            for (int r = 0; r < 4; ++r) {
                const float sc = (r == 1) ? 2.0f * LOG2E : LOG2E;
                bv[r] = (bias[r * 60 + uo] + (r == 2 ? 1.0f : 0.0f)) * sc;
            }
            biasv[tt] = bv;
            const int c = 16 * mt + lm;          // A-operand M-row
            const int u = c >> 2, g = c & 3;
            const float gsc = (g == 1) ? 2.0f * LOG2E : LOG2E;
            #pragma unroll
            for (int s = 0; s < 3; ++s) {
                short8 hv, lv;
                #pragma unroll
                for (int e = 0; e < 8; ++e) {
                    const int k = s * 32 + lk8 + e;
                    float wv = (k < KW) ? wk[k * 240 + g * 60 + u] * gsc : 0.0f;
                    unsigned short hh = bf16rne(wv);
                    hv[e] = (short)hh;
                    lv[e] = (short)bf16rne(wv - bf16tof(hh));
                }
                wh[tt][s] = hv;
                wl[tt][s] = lv;
            }
        } else {
            biasv[tt] = (f32x4){0.f, 0.f, 0.f, 0.f};
            #pragma unroll
            for (int s = 0; s < 3; ++s) { wh[tt][s] = (short8)0; wl[tt][s] = (short8)0; }
        }
    }
    const int u0 = 8 * w + kg;              // unit of tile mt0 output
    const int u1 = 8 * w + 4 + kg;          // unit of tile mt1 output
    const bool t1ok = (2 * w + 1 < 15);

    // ---------------- zero h buffers (h0 = 0, pad cols 60..63 = 0) ----------
    for (int i = tid; i < 2 * BC * HPITCH; i += 512)
        (&Hhi[0][0][0])[i] = 0;

    // ---------------- x fragments: lane owns (row lm, k lk8..lk8+7) ---------
    const float* xrow = x + (size_t)(b0 + lm) * (T_STEPS * F_IN) + lk8;
    float4 va0 = *reinterpret_cast<const float4*>(xrow);
    float4 vb0 = *reinterpret_cast<const float4*>(xrow + 4);
    short8 axh;
    CVTH(va0, vb0, axh)
    // prefetch slot B <- x(1); slot A filled in-loop with x(t+2)
    float4 sBa = *reinterpret_cast<const float4*>(xrow + 1 * F_IN);
    float4 sBb = *reinterpret_cast<const float4*>(xrow + 1 * F_IN + 4);
    float4 sAa, sAb;
    const float* xp2 = xrow + 2 * F_IN;     // bumped by 2*F_IN per step-pair

    float cst0 = 0.f, cst1 = 0.f;           // cell state for (b=lm, u0/u1)
    __syncthreads();

// One LSTM step. Merged 5-deep hi/lo chains (x K-step hi-only). Raw barrier:
// lgkm only; the 2 outstanding x prefetch loads stay in flight across it.
#define STEPX(CUR, NXT, DOLOAD, LA, LB, XOFF, DOCVT, CA, CB, LASTF)             \
    {                                                                           \
        short8 uh1 = *reinterpret_cast<const short8*>(&Hhi[CUR][lm][lk8]);      \
        short8 uh2 = *reinterpret_cast<const short8*>(&Hhi[CUR][lm][32 + lk8]); \
        if (DOLOAD) {                                                           \
            LA = *reinterpret_cast<const float4*>(xp2 + (XOFF));                \
            LB = *reinterpret_cast<const float4*>(xp2 + (XOFF) + 4);            \
        }                                                                       \
        __builtin_amdgcn_s_setprio(1);                                          \
        f32x4 p = MFMA(wh[0][0], axh, biasv[0]);                                \
        f32x4 q = MFMA(wh[1][0], axh, biasv[1]);                                \
        p = MFMA(wh[0][1], uh1, p);                                             \
        q = MFMA(wh[1][1], uh1, q);                                             \
        p = MFMA(wl[0][1], uh1, p);                                             \
        q = MFMA(wl[1][1], uh1, q);                                             \
        p = MFMA(wh[0][2], uh2, p);                                             \
        q = MFMA(wh[1][2], uh2, q);                                             \
        p = MFMA(wl[0][2], uh2, p);                                             \
        q = MFMA(wl[1][2], uh2, q);                                             \
        __builtin_amdgcn_s_setprio(0);                                          \
        CELL2(p, q, h0, h1)                                                     \
        int pk;                                                                 \
        asm("v_cvt_pk_bf16_f32 %0, %1, %2" : "=v"(pk) : "v"(h0), "v"(h1));      \
        if (LASTF) {                                                            \
            Hf[lm][u0] = h0;                                                    \
            if (t1ok) Hf[lm][u1] = h1;                                          \
        } else {                                                                \
            Hhi[NXT][lm][u0] = (short)pk;                                       \
            if (t1ok) Hhi[NXT][lm][u1] = (short)(((unsigned)pk) >> 16);         \
        }                                                                       \
        if (DOCVT) CVTH(CA, CB, axh)                                            \
        BAR()                                                                   \
    }

    for (int t = 0; t < T_STEPS - 2; t += 2) {
        STEPX(0, 1, 1, sAa, sAb, 0,    1, sBa, sBb, 0)  // load x(t+2)->A, cvt x(t+1)<-B
        STEPX(1, 0, 1, sBa, sBb, F_IN, 1, sAa, sAb, 0)  // load x(t+3)->B, cvt x(t+2)<-A
        xp2 += 2 * F_IN;
    }
    // tail: t = 510 (no load; cvt x(511) from B), t = 511 (LAST -> Hf)
    STEPX(0, 1, 0, sAa, sAb, 0, 1, sBa, sBb, 0)
    STEPX(1, 0, 0, sAa, sAb, 0, 0, sBa, sBb, 1)

    // ---------------- epilogue: out[b] = h . dense_w + dense_b --------------
    if (tid < BC) {
        float acc = dense_b[0];
        #pragma unroll 4
        for (int uu = 0; uu < H_DIM; ++uu)
            acc = fmaf(Hf[tid][uu], dense_w[uu], acc);
        out[b0 + tid] = acc;
    }
}

extern "C" void kernel_launch(void* const* d_in, const int* in_sizes, int n_in,
                              void* d_out, int out_size, void* d_ws, size_t ws_size,
                              hipStream_t stream) {
    const float* x       = (const float*)d_in[0];
    const float* wk      = (const float*)d_in[1];
    const float* bias    = (const float*)d_in[2];
    const float* dense_w = (const float*)d_in[3];
    const float* dense_b = (const float*)d_in[4];
    float* out = (float*)d_out;

    lstm_mfma_kernel<<<B_TOTAL / BC, 512, 0, stream>>>(
        x, wk, bias, dense_w, dense_b, out);
}